// Round 9
// baseline (121.393 us; speedup 1.0000x reference)
//
#include <hip/hip_runtime.h>
#include <hip/hip_bf16.h>
#include <stdint.h>

#define ALPHA 0.2f

typedef __attribute__((ext_vector_type(8))) short bf16x8;
typedef __attribute__((ext_vector_type(4))) float f32x4;

__device__ __forceinline__ short f2bf(float f) {
    union { float f; uint32_t u; } c; c.f = f;
    uint32_t u = c.u + 0x7FFF + ((c.u >> 16) & 1);   // round-to-nearest-even
    return (short)(u >> 16);
}

// pack two fp32 -> packed bf16 pair (round-half-up)
__device__ __forceinline__ uint32_t pk_bf16(float lo, float hi) {
    union { float f; uint32_t u; } a, b;
    a.f = lo; b.f = hi;
    return __builtin_amdgcn_perm(b.u + 0x8000u, a.u + 0x8000u, 0x07060302u);
}

// ---------------------------------------------------------------------------
// Kernel 0: pack adj into byte-masks (8 ints -> 1 byte per thread). First 64
// blocks also pre-transpose W (fp32 [k][f]) -> WTg (bf16 [f][k]).
// ---------------------------------------------------------------------------
__global__ __launch_bounds__(256) void pack_adj_kernel(
        const int* __restrict__ adj, uint8_t* __restrict__ bytes,
        const float* __restrict__ W, short* __restrict__ WTg) {
    int t = blockIdx.x * 256 + threadIdx.x;            // 524288 threads
    const int4* a4 = reinterpret_cast<const int4*>(adj) + (size_t)t * 2;
    int4 x0 = a4[0], x1 = a4[1];
    uint32_t m = 0;
    m |= (x0.x > 0) ? 1u   : 0u;  m |= (x0.y > 0) ? 2u   : 0u;
    m |= (x0.z > 0) ? 4u   : 0u;  m |= (x0.w > 0) ? 8u   : 0u;
    m |= (x1.x > 0) ? 16u  : 0u;  m |= (x1.y > 0) ? 32u  : 0u;
    m |= (x1.z > 0) ? 64u  : 0u;  m |= (x1.w > 0) ? 128u : 0u;
    bytes[t] = (uint8_t)m;

    if (blockIdx.x < 64) {
        int idx = blockIdx.x * 256 + threadIdx.x;
        int k = idx >> 7, f = idx & 127;
        WTg[f * 128 + k] = f2bf(W[k * 128 + f]);
    }
}

// ---------------------------------------------------------------------------
// Kernel 1: Wh = h @ W; epilogue: s1/s2 and whT chunk-tiled [b][jc][f][jo].
// XCD swizzle: b = blockIdx & 7. Grid 1024 x 256 thr.
// ---------------------------------------------------------------------------
__global__ __launch_bounds__(256) void wh_kernel(
        const float* __restrict__ h, const short* __restrict__ WTg,
        const float* __restrict__ a, short* __restrict__ whT,
        float* __restrict__ s1g, float* __restrict__ s2g) {
    __shared__ float sred[4][2][16];
    __shared__ short tr[4][32][24];

    int tid = threadIdx.x, wid = tid >> 6, lane = tid & 63;
    int q = lane >> 4, n = lane & 15;
    int bb = blockIdx.x & 7;                           // XCD-local batch
    int tile = blockIdx.x >> 3;                        // 0..127
    int rb = bb * 2048 + tile * 16;                    // global row base
    int row = rb + n;

    f32x4 acc[2] = {};
    #pragma unroll
    for (int kc = 0; kc < 4; ++kc) {
        const float* hp = h + (size_t)row * 128 + kc * 32 + q * 8;
        float4 h0 = reinterpret_cast<const float4*>(hp)[0];
        float4 h1 = reinterpret_cast<const float4*>(hp)[1];
        bf16x8 afrag;
        afrag[0] = f2bf(h0.x); afrag[1] = f2bf(h0.y);
        afrag[2] = f2bf(h0.z); afrag[3] = f2bf(h0.w);
        afrag[4] = f2bf(h1.x); afrag[5] = f2bf(h1.y);
        afrag[6] = f2bf(h1.z); afrag[7] = f2bf(h1.w);
        #pragma unroll
        for (int u = 0; u < 2; ++u) {
            int t = wid * 2 + u;
            bf16x8 bfrag = *reinterpret_cast<const bf16x8*>(
                WTg + (t * 16 + n) * 128 + kc * 32 + q * 8);
            acc[u] = __builtin_amdgcn_mfma_f32_16x16x32_bf16(afrag, bfrag, acc[u], 0, 0, 0);
        }
    }

    float p1[4] = {0.f, 0.f, 0.f, 0.f}, p2[4] = {0.f, 0.f, 0.f, 0.f};
    #pragma unroll
    for (int u = 0; u < 2; ++u) {
        int c = (wid * 2 + u) * 16 + n;
        float a1c = a[c], a2c = a[128 + c];
        #pragma unroll
        for (int r = 0; r < 4; ++r) {
            p1[r] += acc[u][r] * a1c;
            p2[r] += acc[u][r] * a2c;
        }
    }
    #pragma unroll
    for (int d = 1; d < 16; d <<= 1) {
        #pragma unroll
        for (int r = 0; r < 4; ++r) {
            p1[r] += __shfl_xor(p1[r], d);
            p2[r] += __shfl_xor(p2[r], d);
        }
    }
    if (n == 0) {
        #pragma unroll
        for (int r = 0; r < 4; ++r) {
            sred[wid][0][q * 4 + r] = p1[r];
            sred[wid][1][q * 4 + r] = p2[r];
        }
    }

    #pragma unroll
    for (int u = 0; u < 2; ++u)
        #pragma unroll
        for (int r = 0; r < 4; ++r)
            tr[wid][u * 16 + n][q * 4 + r] = f2bf(acc[u][r]);
    __syncthreads();

    if (wid == 0 && lane < 16) {
        float v1 = 0.f, v2 = 0.f;
        #pragma unroll
        for (int v = 0; v < 4; ++v) { v1 += sred[v][0][lane]; v2 += sred[v][1][lane]; }
        s1g[rb + lane] = v1;
        s2g[rb + lane] = v2;
    }

    int jr = rb & 2047;
    int fl = lane & 31, jh = lane >> 5;
    bf16x8 v = *reinterpret_cast<const bf16x8*>(&tr[wid][fl][jh * 8]);
    int f = wid * 32 + fl;
    int jc = jr >> 5, jo = (jr & 31) + jh * 8;
    *reinterpret_cast<bf16x8*>(
        whT + ((size_t)(bb * 64 + jc) * 128 + f) * 32 + jo) = v;
}

// ---------------------------------------------------------------------------
// Kernel 2 (v9): fused masked-softmax attention + PV.
// OCCUPANCY DOUBLED: 16-row blocks, grid 1024 (8 XCD-aligned b x 128
// i-tiles), 4 waves j-split 4x512, __launch_bounds__(256,4) => VGPR<=128,
// LDS 32.2 KB => 4 blocks/CU = 4 waves/SIMD (2x r8).
// Per-chunk memory = ONLY the 8 double-buffered B-frag loads: masks AND s2
// are hoisted into registers once and distributed per-chunk via __shfl.
// ---------------------------------------------------------------------------
__global__ __launch_bounds__(256, 4) void attn_kernel(
        const short* __restrict__ whT, const float* __restrict__ s1g,
        const float* __restrict__ s2g, const uint8_t* __restrict__ adjb,
        float* __restrict__ out) {
    __shared__ f32x4 buf[4][8][64];                    // 32 KB combine buffer
    __shared__ float lds_ds[4][16];

    int wid = threadIdx.x >> 6, lane = threadIdx.x & 63;
    int q = lane >> 4, n = lane & 15;
    int b  = blockIdx.x & 7;                           // XCD-local batch
    int ib = (blockIdx.x >> 3) * 16;                   // i-tile 0..127
    int rowA = ib + n;

    float s1A = s1g[b * 2048 + rowA];
    const float* s2b = s2g + b * 2048;
    int jbase = wid * 512;

    // ---- mask hoist: lane (q,n) holds dwords [q*4..q*4+3] of row n's
    // 512-bit mask slice for this wave's j-range.
    uint4 mregA = *reinterpret_cast<const uint4*>(
        adjb + (size_t)rowA * 256 + wid * 64 + q * 16);
    const uint32_t* mrA = reinterpret_cast<const uint32_t*>(&mregA);

    // ---- s2 hoist: lane l holds s2[jbase + l*8 .. +8) (8 regs)
    float4 s2va = *reinterpret_cast<const float4*>(s2b + jbase + lane * 8);
    float4 s2vb = *reinterpret_cast<const float4*>(s2b + jbase + lane * 8 + 4);
    float s2v[8] = {s2va.x, s2va.y, s2va.z, s2va.w,
                    s2vb.x, s2vb.y, s2vb.z, s2vb.w};

    // chunk-tiled whT: element (b, jc, f, jo) at ((b*64+jc)*128+f)*32+jo
    const short* bpn = whT + (size_t)b * 262144 + n * 32 + q * 8;

    f32x4 accA[8] = {};
    float dsA = 0.f;

    bf16x8 nb[2][8];                                   // B double-buffer
    {   // prologue: chunk 0
        const short* bp = bpn + (size_t)(jbase >> 5) * 4096;
        #pragma unroll
        for (int t = 0; t < 8; ++t)
            nb[0][t] = *reinterpret_cast<const bf16x8*>(bp + t * 512);
    }

    #pragma unroll
    for (int c = 0; c < 16; ++c) {
        const int cur = c & 1, nxt = cur ^ 1;
        int k1 = jbase + ((c + 1) & 15) * 32;
        // ---- issue chunk c+1 B loads (in flight through this chunk)
        const short* bp = bpn + (size_t)(k1 >> 5) * 4096;
        #pragma unroll
        for (int t = 0; t < 8; ++t)
            nb[nxt][t] = *reinterpret_cast<const bf16x8*>(bp + t * 512);

        // ---- mask dword for chunk c via cross-lane shuffle (no memory)
        int srcl = (c >> 2) * 16 + n;                  // lane holding dword c
        uint32_t mA = ((uint32_t)__shfl((int)mrA[c & 3], srcl)) >> (q * 8);

        // ---- s2 for chunk c via cross-lane shuffle (no memory)
        int s2src = c * 4 + q;                         // lane holding this 8-run
        float s2arr[8];
        #pragma unroll
        for (int j = 0; j < 8; ++j) s2arr[j] = __shfl(s2v[j], s2src);

        // ---- compute P for chunk c
        float pA[8];
        #pragma unroll
        for (int j = 0; j < 8; ++j) {
            float eA = s1A + s2arr[j];
            eA = fmaxf(eA, ALPHA * eA);
            float vA = ((mA >> j) & 1) ? __expf(eA) : 0.0f;
            dsA += vA; pA[j] = vA;
        }
        union { uint32_t u[4]; bf16x8 v; } cvA;
        #pragma unroll
        for (int p = 0; p < 4; ++p)
            cvA.u[p] = pk_bf16(pA[2 * p], pA[2 * p + 1]);

        #pragma unroll
        for (int t = 0; t < 8; ++t)
            accA[t] = __builtin_amdgcn_mfma_f32_16x16x32_bf16(cvA.v, nb[cur][t], accA[t], 0, 0, 0);
    }

    // ---- denominators (row m in lanes m, m+16, m+32, m+48)
    dsA += __shfl_xor(dsA, 16); dsA += __shfl_xor(dsA, 32);
    if (q == 0) lds_ds[wid][n] = dsA;

    // ---- combine: all waves stage accA; wave w reduces t-tiles {2w, 2w+1}
    #pragma unroll
    for (int i = 0; i < 8; ++i) buf[wid][i][lane] = accA[i];
    __syncthreads();

    int t0 = wid * 2, t1 = wid * 2 + 1;
    f32x4 rA0 = buf[0][t0][lane] + buf[1][t0][lane] + buf[2][t0][lane] + buf[3][t0][lane];
    f32x4 rA1 = buf[0][t1][lane] + buf[1][t1][lane] + buf[2][t1][lane] + buf[3][t1][lane];

    float dAt = lds_ds[0][n] + lds_ds[1][n] + lds_ds[2][n] + lds_ds[3][n];
    float rdA[4];
    #pragma unroll
    for (int r = 0; r < 4; ++r)
        rdA[r] = 1.0f / __shfl(dAt, q * 4 + r);

    size_t ob = ((size_t)b * 2048 + ib) * 128;
    #pragma unroll
    for (int r = 0; r < 4; ++r) {
        out[ob + (size_t)(q * 4 + r) * 128 + t0 * 16 + n] = rA0[r] * rdA[r];
        out[ob + (size_t)(q * 4 + r) * 128 + t1 * 16 + n] = rA1[r] * rdA[r];
    }
}

// ---------------------------------------------------------------------------
extern "C" void kernel_launch(void* const* d_in, const int* in_sizes, int n_in,
                              void* d_out, int out_size, void* d_ws, size_t ws_size,
                              hipStream_t stream) {
    const float* h   = (const float*)d_in[0];   // [8][2048][128] f32
    const int*   adj = (const int*)d_in[1];     // [2048][2048] i32
    const float* W   = (const float*)d_in[2];   // [128][128] f32
    const float* a   = (const float*)d_in[3];   // [256][1] f32
    float* out = (float*)d_out;                 // [8][2048][128] f32

    char* ws = (char*)d_ws;
    short* whT = (short*)ws;                                  // 4 MB  bf16 whT (chunk-tiled)
    float* s1  = (float*)(ws + 4194304);                      // 64 KB
    float* s2  = (float*)(ws + 4259840);                      // 64 KB
    uint8_t* bytes = (uint8_t*)(ws + 4325376);                // 512 KB

    // WT scratch in the tail of d_out (32 KB); wh reads it before attn
    // overwrites d_out. Same-stream ordering makes this safe.
    short* WTg = (short*)d_out + (4194304 - 16384);

    pack_adj_kernel<<<2048, 256, 0, stream>>>(adj, bytes, W, WTg);
    wh_kernel<<<1024, 256, 0, stream>>>(h, WTg, a, whT, s1, s2);
    attn_kernel<<<1024, 256, 0, stream>>>(whT, s1, s2, bytes, out);
}

// Round 10
// 114.602 us; speedup vs baseline: 1.0593x; 1.0593x over previous
//
#include <hip/hip_runtime.h>
#include <hip/hip_bf16.h>
#include <stdint.h>

#define ALPHA 0.2f

typedef __attribute__((ext_vector_type(8))) short bf16x8;
typedef __attribute__((ext_vector_type(4))) float f32x4;

__device__ __forceinline__ short f2bf(float f) {
    union { float f; uint32_t u; } c; c.f = f;
    uint32_t u = c.u + 0x7FFF + ((c.u >> 16) & 1);   // round-to-nearest-even
    return (short)(u >> 16);
}

// pack two fp32 -> packed bf16 pair (round-half-up)
__device__ __forceinline__ uint32_t pk_bf16(float lo, float hi) {
    union { float f; uint32_t u; } a, b;
    a.f = lo; b.f = hi;
    return __builtin_amdgcn_perm(b.u + 0x8000u, a.u + 0x8000u, 0x07060302u);
}

// async global->LDS, 16 B per lane. l must be wave-uniform; g is per-lane.
__device__ __forceinline__ void gload_lds16(const void* g, void* l) {
    __builtin_amdgcn_global_load_lds(
        (const __attribute__((address_space(1))) void*)g,
        (__attribute__((address_space(3))) void*)l, 16, 0, 0);
}

// ---------------------------------------------------------------------------
// Kernel 0: pack adj into byte-masks (8 ints -> 1 byte per thread). First 64
// blocks also pre-transpose W (fp32 [k][f]) -> WTg (bf16 [f][k]).
// ---------------------------------------------------------------------------
__global__ __launch_bounds__(256) void pack_adj_kernel(
        const int* __restrict__ adj, uint8_t* __restrict__ bytes,
        const float* __restrict__ W, short* __restrict__ WTg) {
    int t = blockIdx.x * 256 + threadIdx.x;            // 524288 threads
    const int4* a4 = reinterpret_cast<const int4*>(adj) + (size_t)t * 2;
    int4 x0 = a4[0], x1 = a4[1];
    uint32_t m = 0;
    m |= (x0.x > 0) ? 1u   : 0u;  m |= (x0.y > 0) ? 2u   : 0u;
    m |= (x0.z > 0) ? 4u   : 0u;  m |= (x0.w > 0) ? 8u   : 0u;
    m |= (x1.x > 0) ? 16u  : 0u;  m |= (x1.y > 0) ? 32u  : 0u;
    m |= (x1.z > 0) ? 64u  : 0u;  m |= (x1.w > 0) ? 128u : 0u;
    bytes[t] = (uint8_t)m;

    if (blockIdx.x < 64) {
        int idx = blockIdx.x * 256 + threadIdx.x;
        int k = idx >> 7, f = idx & 127;
        WTg[f * 128 + k] = f2bf(W[k * 128 + f]);
    }
}

// ---------------------------------------------------------------------------
// Kernel 1: Wh = h @ W; epilogue: s1/s2 and whT in MFMA-frag-ordered chunk
// layout: chunk (b,jc) is 8 KB; element (f, jo) at
//   chunkbase + t*512 + qg*128 + n*8 + jj   (shorts)
// where t=f>>4, n=f&15, qg=jo>>3, jj=jo&7 — so attn's LDS ds_read_b128 at
// lane*16 is the conflict-free m97 pattern. XCD swizzle: b = blockIdx & 7.
// ---------------------------------------------------------------------------
__global__ __launch_bounds__(256) void wh_kernel(
        const float* __restrict__ h, const short* __restrict__ WTg,
        const float* __restrict__ a, short* __restrict__ whT,
        float* __restrict__ s1g, float* __restrict__ s2g) {
    __shared__ float sred[4][2][16];
    __shared__ short tr[4][32][24];

    int tid = threadIdx.x, wid = tid >> 6, lane = tid & 63;
    int q = lane >> 4, n = lane & 15;
    int bb = blockIdx.x & 7;                           // XCD-local batch
    int tile = blockIdx.x >> 3;                        // 0..127
    int rb = bb * 2048 + tile * 16;                    // global row base
    int row = rb + n;

    f32x4 acc[2] = {};
    #pragma unroll
    for (int kc = 0; kc < 4; ++kc) {
        const float* hp = h + (size_t)row * 128 + kc * 32 + q * 8;
        float4 h0 = reinterpret_cast<const float4*>(hp)[0];
        float4 h1 = reinterpret_cast<const float4*>(hp)[1];
        bf16x8 afrag;
        afrag[0] = f2bf(h0.x); afrag[1] = f2bf(h0.y);
        afrag[2] = f2bf(h0.z); afrag[3] = f2bf(h0.w);
        afrag[4] = f2bf(h1.x); afrag[5] = f2bf(h1.y);
        afrag[6] = f2bf(h1.z); afrag[7] = f2bf(h1.w);
        #pragma unroll
        for (int u = 0; u < 2; ++u) {
            int t = wid * 2 + u;
            bf16x8 bfrag = *reinterpret_cast<const bf16x8*>(
                WTg + (t * 16 + n) * 128 + kc * 32 + q * 8);
            acc[u] = __builtin_amdgcn_mfma_f32_16x16x32_bf16(afrag, bfrag, acc[u], 0, 0, 0);
        }
    }

    float p1[4] = {0.f, 0.f, 0.f, 0.f}, p2[4] = {0.f, 0.f, 0.f, 0.f};
    #pragma unroll
    for (int u = 0; u < 2; ++u) {
        int c = (wid * 2 + u) * 16 + n;
        float a1c = a[c], a2c = a[128 + c];
        #pragma unroll
        for (int r = 0; r < 4; ++r) {
            p1[r] += acc[u][r] * a1c;
            p2[r] += acc[u][r] * a2c;
        }
    }
    #pragma unroll
    for (int d = 1; d < 16; d <<= 1) {
        #pragma unroll
        for (int r = 0; r < 4; ++r) {
            p1[r] += __shfl_xor(p1[r], d);
            p2[r] += __shfl_xor(p2[r], d);
        }
    }
    if (n == 0) {
        #pragma unroll
        for (int r = 0; r < 4; ++r) {
            sred[wid][0][q * 4 + r] = p1[r];
            sred[wid][1][q * 4 + r] = p2[r];
        }
    }

    #pragma unroll
    for (int u = 0; u < 2; ++u)
        #pragma unroll
        for (int r = 0; r < 4; ++r)
            tr[wid][u * 16 + n][q * 4 + r] = f2bf(acc[u][r]);
    __syncthreads();

    if (wid == 0 && lane < 16) {
        float v1 = 0.f, v2 = 0.f;
        #pragma unroll
        for (int v = 0; v < 4; ++v) { v1 += sred[v][0][lane]; v2 += sred[v][1][lane]; }
        s1g[rb + lane] = v1;
        s2g[rb + lane] = v2;
    }

    int jr = rb & 2047;
    int fl = lane & 31, jh = lane >> 5;
    bf16x8 v = *reinterpret_cast<const bf16x8*>(&tr[wid][fl][jh * 8]);
    int f = wid * 32 + fl;
    int t = f >> 4, nn = f & 15;
    int jc = jr >> 5;
    int qg = ((jr & 31) >> 3) + jh;                    // jo>>3 for this 8-run
    *reinterpret_cast<bf16x8*>(
        whT + (size_t)(bb * 64 + jc) * 4096 + t * 512 + qg * 128 + nn * 8) = v;
}

// ---------------------------------------------------------------------------
// Kernel 2 (v10): fused masked-softmax attention + PV, GEMM-style LDS
// staging. Grid 256 (8 XCD-aligned b x 32 i-tiles of 64 rows) x 256 thr.
// Wave w owns rows ib+w*16..+16 over the FULL j range (no combine!).
// Per step (4 chunks = 32 KB): block stages B once via global_load_lds
// (double-buffered), all 4 waves consume via conflict-free ds_read_b128.
// L2 B-traffic: 512 KB per block (4x less than r9). Masks/s2 prefetched
// into rotating register slots (compile-time indices).
// ---------------------------------------------------------------------------
__global__ __launch_bounds__(256) void attn_kernel(
        const short* __restrict__ whT, const float* __restrict__ s1g,
        const float* __restrict__ s2g, const uint8_t* __restrict__ adjb,
        float* __restrict__ out) {
    __shared__ char sbuf[2][32768];                    // 64 KB staging

    int wid = threadIdx.x >> 6, lane = threadIdx.x & 63;
    int q = lane >> 4, n = lane & 15;
    int b  = blockIdx.x & 7;                           // XCD-local batch
    int ib = (blockIdx.x >> 3) * 64;                   // i-tile base
    int rowA = ib + wid * 16 + n;                      // this wave's row (m=n)

    float s1A = s1g[b * 2048 + rowA];
    const float* s2b = s2g + b * 2048;
    const uint32_t* admA = reinterpret_cast<const uint32_t*>(
        adjb + (size_t)rowA * 256);
    const char* gbase = reinterpret_cast<const char*>(whT) + (size_t)b * 524288;

    f32x4 acc[8] = {};
    float ds = 0.f;

    // mask/s2 rotating slots for chunks c..c+3 (compile-time indices)
    uint32_t mw[4];
    float4 s2l[4], s2h[4];
    #pragma unroll
    for (int u = 0; u < 4; ++u) {
        mw[u] = admA[u];
        s2l[u] = *reinterpret_cast<const float4*>(s2b + u * 32 + q * 8);
        s2h[u] = *reinterpret_cast<const float4*>(s2b + u * 32 + q * 8 + 4);
    }

    // stage step 0 (chunks 0..3): wave w stages 8 KB as 8x 1KB identity copies
    {
        const char* g = gbase + wid * 8192 + lane * 16;
        char* l = &sbuf[0][wid * 8192];
        #pragma unroll
        for (int i = 0; i < 8; ++i)
            gload_lds16(g + i * 1024, l + i * 1024);
    }
    __syncthreads();

    for (int s = 0; s < 16; ++s) {
        int cur = s & 1;
        if (s < 15) {                                  // stage step s+1
            const char* g = gbase + (size_t)(s + 1) * 32768 + wid * 8192 + lane * 16;
            char* l = &sbuf[cur ^ 1][wid * 8192];
            #pragma unroll
            for (int i = 0; i < 8; ++i)
                gload_lds16(g + i * 1024, l + i * 1024);
        }
        const char* lb = sbuf[cur];
        #pragma unroll
        for (int u = 0; u < 4; ++u) {
            int c = s * 4 + u;
            // B frags from LDS: lane*16-contiguous (conflict-free b128)
            bf16x8 nb[8];
            const char* cb = lb + u * 8192 + lane * 16;
            #pragma unroll
            for (int t = 0; t < 8; ++t)
                nb[t] = *reinterpret_cast<const bf16x8*>(cb + t * 1024);

            uint32_t mA = mw[u] >> (q * 8);
            float s2arr[8] = {s2l[u].x, s2l[u].y, s2l[u].z, s2l[u].w,
                              s2h[u].x, s2h[u].y, s2h[u].z, s2h[u].w};

            // prefetch slot u for chunk c+4 (clamped; tail values unused)
            int cn = c + 4; if (cn > 63) cn = 63;
            mw[u] = admA[cn];
            s2l[u] = *reinterpret_cast<const float4*>(s2b + cn * 32 + q * 8);
            s2h[u] = *reinterpret_cast<const float4*>(s2b + cn * 32 + q * 8 + 4);

            // P for chunk c (rows = this wave's 16, k = q*8+j)
            float p[8];
            #pragma unroll
            for (int j = 0; j < 8; ++j) {
                float e = s1A + s2arr[j];
                e = fmaxf(e, ALPHA * e);
                float v = ((mA >> j) & 1) ? __expf(e) : 0.0f;
                ds += v; p[j] = v;
            }
            union { uint32_t u32[4]; bf16x8 v; } cv;
            #pragma unroll
            for (int pp = 0; pp < 4; ++pp)
                cv.u32[pp] = pk_bf16(p[2 * pp], p[2 * pp + 1]);

            #pragma unroll
            for (int t = 0; t < 8; ++t)
                acc[t] = __builtin_amdgcn_mfma_f32_16x16x32_bf16(cv.v, nb[t], acc[t], 0, 0, 0);
        }
        __syncthreads();
    }

    // ---- denominators (row m in lanes m, m+16, m+32, m+48) — wave-private
    ds += __shfl_xor(ds, 16); ds += __shfl_xor(ds, 32);
    float rd[4];
    #pragma unroll
    for (int r = 0; r < 4; ++r) rd[r] = 1.0f / __shfl(ds, q * 4 + r);

    size_t ob = ((size_t)b * 2048 + ib + wid * 16) * 128;
    #pragma unroll
    for (int t = 0; t < 8; ++t)
        #pragma unroll
        for (int r = 0; r < 4; ++r)
            out[ob + (size_t)(q * 4 + r) * 128 + t * 16 + n] = acc[t][r] * rd[r];
}

// ---------------------------------------------------------------------------
extern "C" void kernel_launch(void* const* d_in, const int* in_sizes, int n_in,
                              void* d_out, int out_size, void* d_ws, size_t ws_size,
                              hipStream_t stream) {
    const float* h   = (const float*)d_in[0];   // [8][2048][128] f32
    const int*   adj = (const int*)d_in[1];     // [2048][2048] i32
    const float* W   = (const float*)d_in[2];   // [128][128] f32
    const float* a   = (const float*)d_in[3];   // [256][1] f32
    float* out = (float*)d_out;                 // [8][2048][128] f32

    char* ws = (char*)d_ws;
    short* whT = (short*)ws;                                  // 4 MB  bf16 whT (chunk-tiled)
    float* s1  = (float*)(ws + 4194304);                      // 64 KB
    float* s2  = (float*)(ws + 4259840);                      // 64 KB
    uint8_t* bytes = (uint8_t*)(ws + 4325376);                // 512 KB

    // WT scratch in the tail of d_out (32 KB); wh reads it before attn
    // overwrites d_out. Same-stream ordering makes this safe.
    short* WTg = (short*)d_out + (4194304 - 16384);

    pack_adj_kernel<<<2048, 256, 0, stream>>>(adj, bytes, W, WTg);
    wh_kernel<<<1024, 256, 0, stream>>>(h, WTg, a, whT, s1, s2);
    attn_kernel<<<256, 256, 0, stream>>>(whT, s1, s2, bytes, out);
}